// Round 6
// baseline (1239.857 us; speedup 1.0000x reference)
//
#include <hip/hip_runtime.h>
#include <hip/hip_bf16.h>

#define B_ 4
#define S_ 2048
#define D_ 512
#define H_ 8
#define DK_ 64
#define M_ (B_*S_)   // 8192 rows

typedef float f32x4 __attribute__((ext_vector_type(4)));
typedef __bf16 bf16x8 __attribute__((ext_vector_type(8)));
typedef unsigned short u16x8 __attribute__((ext_vector_type(8)));

static __device__ __forceinline__ unsigned short f2bf(float x) {
    return __builtin_bit_cast(unsigned short, __float2bfloat16(x));
}
static __device__ __forceinline__ float bf2f(unsigned short u) {
    return __bfloat162float(__builtin_bit_cast(__hip_bfloat16, u));
}
static __device__ __forceinline__ bf16x8 ldfrag(const unsigned short* p) {
    return __builtin_bit_cast(bf16x8, *(const u16x8*)p);
}

// async global->LDS, 16B per lane; LDS dest = wave-uniform base + lane*16
typedef __attribute__((address_space(1))) const unsigned int gu32;
typedef __attribute__((address_space(3))) unsigned int lu32;
static __device__ __forceinline__ void gl_lds16(const unsigned short* g, unsigned short* l) {
    __builtin_amdgcn_global_load_lds((gu32*)g, (lu32*)l, 16, 0, 0);
}

// split 8 fp32 -> hi (truncated bf16) / lo (bf16 of exact residual)
static __device__ __forceinline__ void split8(const float4 x0, const float4 x1,
                                              u16x8& h, u16x8& l) {
    float f[8] = {x0.x, x0.y, x0.z, x0.w, x1.x, x1.y, x1.z, x1.w};
    #pragma unroll
    for (int j = 0; j < 8; ++j) {
        const unsigned u = __builtin_bit_cast(unsigned, f[j]);
        h[j] = (unsigned short)(u >> 16);
        const float hf = __builtin_bit_cast(float, u & 0xFFFF0000u);
        l[j] = (unsigned short)(__builtin_bit_cast(unsigned, f[j] - hf) >> 16);
    }
}

// ---------------------------------------------------------------------------
// Prep: split q,k,v [8192x512] fp32 -> hi/lo bf16 (row-major preserved)
// ---------------------------------------------------------------------------
__global__ __launch_bounds__(256) void split_x3(
    const float* __restrict__ xq, const float* __restrict__ xk, const float* __restrict__ xv,
    unsigned short* __restrict__ qh, unsigned short* __restrict__ qlo,
    unsigned short* __restrict__ kh, unsigned short* __restrict__ klo,
    unsigned short* __restrict__ vh, unsigned short* __restrict__ vlo)
{
    const size_t t = (size_t)blockIdx.x * 256 + threadIdx.x;   // < 524288
    const int z = blockIdx.y;
    const float* in = z == 0 ? xq : z == 1 ? xk : xv;
    unsigned short* oh = z == 0 ? qh : z == 1 ? kh : vh;
    unsigned short* ol = z == 0 ? qlo : z == 1 ? klo : vlo;
    const float4* p = (const float4*)(in + t * 8);
    u16x8 hh, ll;
    split8(p[0], p[1], hh, ll);
    ((u16x8*)oh)[t] = hh;
    ((u16x8*)ol)[t] = ll;
}

// Prep: split Wq,Wk,Wv into concatenated [1536x512] hi/lo; Wo separate
__global__ __launch_bounds__(256) void split_w4(
    const float* __restrict__ Wq, const float* __restrict__ Wk,
    const float* __restrict__ Wv, const float* __restrict__ Wo,
    unsigned short* __restrict__ Wcat_h, unsigned short* __restrict__ Wcat_l,
    unsigned short* __restrict__ Wo_h, unsigned short* __restrict__ Wo_l)
{
    const size_t t = (size_t)blockIdx.x * 256 + threadIdx.x;   // < 32768
    const int z = blockIdx.y;
    const float* in = z == 0 ? Wq : z == 1 ? Wk : z == 2 ? Wv : Wo;
    unsigned short* oh = z < 3 ? Wcat_h + (size_t)z * 262144 : Wo_h;
    unsigned short* ol = z < 3 ? Wcat_l + (size_t)z * 262144 : Wo_l;
    const float4* p = (const float4*)(in + t * 8);
    u16x8 hh, ll;
    split8(p[0], p[1], hh, ll);
    ((u16x8*)oh)[t] = hh;
    ((u16x8*)ol)[t] = ll;
}

// Prep: pack mask int32 [B,S,S] -> bitmask u64 (bit j = mask!=0), 64 cols/word
__global__ __launch_bounds__(256) void mask_pack(
    const int* __restrict__ mask, unsigned long long* __restrict__ bits)
{
    const size_t t = (size_t)blockIdx.x * 256 + threadIdx.x;   // < B*S*S
    const int m = mask[t];
    const unsigned long long w = __ballot(m != 0);
    if ((threadIdx.x & 63) == 0) bits[t >> 6] = w;
}

// ---------------------------------------------------------------------------
// hi/lo-split MFMA GEMM v4 (unchanged structure): Y = X @ W^T + bias
// T4 counted vmcnt double-buffer; LDS chunk-swizzle both-sides.
// fused=1: QKV. q,k -> head-layout hi/lo. v -> TRANSPOSED head layout
//          vT[b,h,dk,s] (feeds barrier-free attention PV directly).
// fused=0: out-proj (N=512, fp32 out)
// ---------------------------------------------------------------------------
#define GBK 32
__global__ __launch_bounds__(256, 2) void gemm_hl(
    const unsigned short* __restrict__ qXh, const unsigned short* __restrict__ qXl,
    const unsigned short* __restrict__ kXh, const unsigned short* __restrict__ kXl,
    const unsigned short* __restrict__ vXh, const unsigned short* __restrict__ vXl,
    const unsigned short* __restrict__ Wh, const unsigned short* __restrict__ Wl,
    const float* __restrict__ b0, const float* __restrict__ b1, const float* __restrict__ b2,
    float* __restrict__ Yf32,
    unsigned short* __restrict__ q_hi, unsigned short* __restrict__ q_lo,
    unsigned short* __restrict__ k_hi, unsigned short* __restrict__ k_lo,
    unsigned short* __restrict__ vT, int fused)
{
    // [buf][arr][128*32] arr: 0=Ah 1=Al 2=Bh 3=Bl   (64 KB total)
    __shared__ __align__(16) unsigned short lds[2][4][128 * GBK];

    const int tid = threadIdx.x;
    const int lane = tid & 63, wv = tid >> 6;
    const int quad = lane >> 4, col = lane & 15;
    const int wm = wv >> 1, wn = wv & 1;
    const int m0 = blockIdx.x * 128;
    const int n0g = blockIdx.y * 128;
    const int mat = fused ? (n0g >> 9) : 0;   // block-uniform
    const unsigned short* Xh = (!fused || mat == 0) ? qXh : (mat == 1 ? kXh : vXh);
    const unsigned short* Xl = (!fused || mat == 0) ? qXl : (mat == 1 ? kXl : vXl);

    // staging lane map: 1024B gl_lds = 16 rows x 64B; lane l -> row l>>2,
    // LDS 16B slot l&3; source chunk pre-swizzled: (l&3) ^ ((l>>3)&3)
    const int rsub = lane >> 2;
    const int csw = (((lane & 3) ^ ((lane >> 3) & 3))) * 8;   // elem offset

    f32x4 acc[4][4] = {};

    auto STAGE = [&](int t, int buf) {
        const int kt = t * GBK;
        #pragma unroll
        for (int i = 0; i < 2; ++i) {
            const int r0 = wv * 32 + i * 16;           // wave-uniform row base
            gl_lds16(Xh + (size_t)(m0 + r0 + rsub) * D_ + kt + csw, &lds[buf][0][r0 * GBK]);
            gl_lds16(Xl + (size_t)(m0 + r0 + rsub) * D_ + kt + csw, &lds[buf][1][r0 * GBK]);
            gl_lds16(Wh + (size_t)(n0g + r0 + rsub) * D_ + kt + csw, &lds[buf][2][r0 * GBK]);
            gl_lds16(Wl + (size_t)(n0g + r0 + rsub) * D_ + kt + csw, &lds[buf][3][r0 * GBK]);
        }
    };

    auto COMPUTE = [&](int buf) {
        bf16x8 ah[4], al[4], bh[4], bl[4];
        #pragma unroll
        for (int i = 0; i < 4; ++i) {
            const int ra = wm * 64 + i * 16 + col;
            const int ca = (quad ^ ((ra >> 1) & 3)) * 8;   // swizzled chunk
            ah[i] = ldfrag(&lds[buf][0][ra * GBK + ca]);
            al[i] = ldfrag(&lds[buf][1][ra * GBK + ca]);
            const int rb = wn * 64 + i * 16 + col;
            const int cb = (quad ^ ((rb >> 1) & 3)) * 8;
            bh[i] = ldfrag(&lds[buf][2][rb * GBK + cb]);
            bl[i] = ldfrag(&lds[buf][3][rb * GBK + cb]);
        }
        __builtin_amdgcn_s_setprio(1);
        #pragma unroll
        for (int i = 0; i < 4; ++i)
            #pragma unroll
            for (int j = 0; j < 4; ++j) {
                acc[i][j] = __builtin_amdgcn_mfma_f32_16x16x32_bf16(ah[i], bh[j], acc[i][j], 0, 0, 0);
                acc[i][j] = __builtin_amdgcn_mfma_f32_16x16x32_bf16(al[i], bh[j], acc[i][j], 0, 0, 0);
                acc[i][j] = __builtin_amdgcn_mfma_f32_16x16x32_bf16(ah[i], bl[j], acc[i][j], 0, 0, 0);
            }
        __builtin_amdgcn_s_setprio(0);
    };

    STAGE(0, 0);
    STAGE(1, 1);
    int cur = 0;
    for (int t = 0; t < 16; ++t) {
        // buf(cur)'s 8 loads are the oldest; 8 newer (next buf) may stay in flight
        if (t < 15) asm volatile("s_waitcnt vmcnt(8)\n\ts_barrier" ::: "memory");
        else        asm volatile("s_waitcnt vmcnt(0)\n\ts_barrier" ::: "memory");
        COMPUTE(cur);
        asm volatile("s_barrier" ::: "memory");   // all waves done reading buf(cur)
        if (t < 14) STAGE(t + 2, cur);            // overwrite; stays in flight
        cur ^= 1;
    }

    // epilogue: C/D layout col=lane&15 (n), row=quad*4+r (m)
    #pragma unroll
    for (int j = 0; j < 4; ++j) {
        const int ng = n0g + wn * 64 + j * 16 + col;
        const int n = fused ? (ng & 511) : ng;
        const float bias = fused ? (mat == 0 ? b0[n] : mat == 1 ? b1[n] : b2[n]) : b0[n];
        #pragma unroll
        for (int i = 0; i < 4; ++i) {
            #pragma unroll
            for (int r = 0; r < 4; ++r) {
                const int m = m0 + wm * 64 + i * 16 + quad * 4 + r;
                const float vv = acc[i][j][r] + bias;
                if (!fused) {
                    Yf32[(size_t)m * D_ + n] = vv;
                } else {
                    const int bi = m >> 11, si = m & (S_ - 1);
                    const int hh = n >> 6, dk = n & 63;
                    const unsigned short hi = f2bf(vv);
                    if (mat == 2) {
                        // transposed head layout [b,h,dk,s]
                        const size_t idxT = (((size_t)bi * H_ + hh) * DK_ + dk) * S_ + si;
                        vT[idxT] = hi;
                    } else {
                        const size_t idx = (((size_t)bi * H_ + hh) * S_ + si) * DK_ + dk;
                        if (mat == 0) { q_hi[idx] = hi; q_lo[idx] = f2bf(vv - bf2f(hi)); }
                        else          { k_hi[idx] = hi; k_lo[idx] = f2bf(vv - bf2f(hi)); }
                    }
                }
            }
        }
    }
}

// ---------------------------------------------------------------------------
// Flash-style two-pass MFMA attention, v5 — BARRIER-FREE, STAGING-FREE.
// Per (b,h), K hi/lo (512KB) and vT (256KB) are L1/L2-resident: MFMA B-operand
// fragments are loaded DIRECTLY from global (16B coalesced, 16B aligned).
// V is consumed from the pre-transposed vT[b,h,dk,s] the QKV GEMM emitted,
// so the 8-way-bank-conflict LDS V-transpose is gone. The only LDS is the
// same-wave P transpose (sP for PV A-operand, sPF for coalesced scores
// stores) -> ZERO s_barrier in the kernel; waves free-run and the compiler
// pipelines fragment loads under MFMA.
// ---------------------------------------------------------------------------
__global__ __launch_bounds__(256) void attn_mfma_kernel(
    const unsigned short* __restrict__ q_hi, const unsigned short* __restrict__ q_lo,
    const unsigned short* __restrict__ k_hi, const unsigned short* __restrict__ k_lo,
    const unsigned short* __restrict__ vT, const unsigned long long* __restrict__ mbits,
    float* __restrict__ scores,
    unsigned short* __restrict__ ch, unsigned short* __restrict__ cl)
{
    __shared__ __align__(16) unsigned short sP[64][72];   // [qrow][kpos], same-wave
    __shared__ __align__(16) float sPF[64][68];           // fp32 p, same-wave

    const int tid = threadIdx.x;
    const int q0 = blockIdx.x * 64;
    const int h = blockIdx.y, b = blockIdx.z;
    const size_t bh = (size_t)b * H_ + h;
    const int wv = tid >> 6, lane = tid & 63, quad = lane >> 4, col = lane & 15;

    // ---- Q fragments in registers (A-operand: [lane&15=row][quad*8+j=k]) ----
    bf16x8 qh[2], ql[2];
    {
        const size_t qb = (bh * S_ + q0 + wv * 16 + col) * DK_;
        qh[0] = ldfrag(q_hi + qb + quad * 8);
        qh[1] = ldfrag(q_hi + qb + 32 + quad * 8);
        ql[0] = ldfrag(q_lo + qb + quad * 8);
        ql[1] = ldfrag(q_lo + qb + 32 + quad * 8);
    }

    const size_t mrow_base = ((size_t)b * S_ + q0 + wv * 16 + quad * 4) * (S_ / 64);
    const unsigned short* kH = k_hi + bh * S_ * DK_;
    const unsigned short* kL = k_lo + bh * S_ * DK_;
    const unsigned short* vB = vT + bh * DK_ * S_;

    // QK^T S-tile straight from global K fragments
    auto compute_svals = [&](int kt, const unsigned long long* mw, float sv[4][4]) {
        #pragma unroll
        for (int t = 0; t < 4; ++t) {
            const size_t krow = (size_t)(kt * 64 + t * 16 + col) * DK_;
            f32x4 acc = {0.f, 0.f, 0.f, 0.f};
            #pragma unroll
            for (int kci = 0; kci < 2; ++kci) {
                bf16x8 bhf = ldfrag(kH + krow + kci * 32 + quad * 8);
                bf16x8 blf = ldfrag(kL + krow + kci * 32 + quad * 8);
                __builtin_amdgcn_s_setprio(1);
                acc = __builtin_amdgcn_mfma_f32_16x16x32_bf16(qh[kci], bhf, acc, 0, 0, 0);
                acc = __builtin_amdgcn_mfma_f32_16x16x32_bf16(qh[kci], blf, acc, 0, 0, 0);
                acc = __builtin_amdgcn_mfma_f32_16x16x32_bf16(ql[kci], bhf, acc, 0, 0, 0);
                __builtin_amdgcn_s_setprio(0);
            }
            #pragma unroll
            for (int r = 0; r < 4; ++r) {
                float s = acc[r] * 0.125f;
                if (!((mw[r] >> (t * 16 + col)) & 1ull)) s = -1e9f;
                sv[t][r] = s;
            }
        }
    };

    // ---- pass 1: row max & sum (no LDS, no barriers) ----
    float m_run[4], l_run[4];
    #pragma unroll
    for (int r = 0; r < 4; ++r) { m_run[r] = -1e30f; l_run[r] = 0.f; }

    for (int kt = 0; kt < 32; ++kt) {
        unsigned long long mw[4];
        #pragma unroll
        for (int r = 0; r < 4; ++r) mw[r] = mbits[mrow_base + (size_t)r * (S_ / 64) + kt];
        float sv[4][4];
        compute_svals(kt, mw, sv);
        #pragma unroll
        for (int r = 0; r < 4; ++r) {
            float tm = fmaxf(fmaxf(sv[0][r], sv[1][r]), fmaxf(sv[2][r], sv[3][r]));
            #pragma unroll
            for (int mm = 1; mm < 16; mm <<= 1) tm = fmaxf(tm, __shfl_xor(tm, mm));
            const float nm = fmaxf(m_run[r], tm);
            float ts = __expf(sv[0][r] - nm) + __expf(sv[1][r] - nm)
                     + __expf(sv[2][r] - nm) + __expf(sv[3][r] - nm);
            #pragma unroll
            for (int mm = 1; mm < 16; mm <<= 1) ts += __shfl_xor(ts, mm);
            l_run[r] = l_run[r] * __expf(m_run[r] - nm) + ts;
            m_run[r] = nm;
        }
    }
    float inv_l[4];
    #pragma unroll
    for (int r = 0; r < 4; ++r) inv_l[r] = 1.f / l_run[r];

    // ---- pass 2: recompute S, write scores (coalesced, nt), P@V ----
    f32x4 oacc[4] = {};
    for (int kt = 0; kt < 32; ++kt) {
        unsigned long long mw[4];
        #pragma unroll
        for (int r = 0; r < 4; ++r) mw[r] = mbits[mrow_base + (size_t)r * (S_ / 64) + kt];
        float sv[4][4];
        compute_svals(kt, mw, sv);
        #pragma unroll
        for (int t = 0; t < 4; ++t) {
            #pragma unroll
            for (int r = 0; r < 4; ++r) {
                const float p = __expf(sv[t][r] - m_run[r]) * inv_l[r];
                sPF[wv * 16 + quad * 4 + r][t * 16 + col] = p;
                sP[wv * 16 + quad * 4 + r][t * 16 + col] = f2bf(p);
            }
        }
        // coalesced nontemporal write: wave's own 16 rows, 8 rows x 128B per instr
        #pragma unroll
        for (int rg = 0; rg < 2; ++rg)
            #pragma unroll
            for (int hf = 0; hf < 2; ++hf) {
                const int rl = wv * 16 + rg * 8 + (lane >> 3);
                const int cf = hf * 32 + (lane & 7) * 4;
                const f32x4 pw = *(const f32x4*)&sPF[rl][cf];
                __builtin_nontemporal_store(pw,
                    (f32x4*)&scores[(bh * S_ + q0 + rl) * S_ + kt * 64 + cf]);
            }
        // P@V: A from sP (same-wave LDS, in-order), B straight from global vT
        #pragma unroll
        for (int to = 0; to < 4; ++to) {
            const size_t vrow = (size_t)(to * 16 + col) * S_ + kt * 64;
            #pragma unroll
            for (int kc = 0; kc < 64; kc += 32) {
                bf16x8 a  = ldfrag(&sP[wv * 16 + col][kc + quad * 8]);
                bf16x8 bb = ldfrag(vB + vrow + kc + quad * 8);
                __builtin_amdgcn_s_setprio(1);
                oacc[to] = __builtin_amdgcn_mfma_f32_16x16x32_bf16(a, bb, oacc[to], 0, 0, 0);
                __builtin_amdgcn_s_setprio(0);
            }
        }
    }

    // ---- epilogue: O -> concat hi/lo bf16 [B,S,D] ----
    #pragma unroll
    for (int to = 0; to < 4; ++to) {
        #pragma unroll
        for (int r = 0; r < 4; ++r) {
            const int qg = q0 + wv * 16 + quad * 4 + r;
            const size_t idx = ((size_t)b * S_ + qg) * D_ + h * DK_ + to * 16 + col;
            const float o = oacc[to][r];
            const unsigned short oh16 = f2bf(o);
            ch[idx] = oh16;
            cl[idx] = f2bf(o - bf2f(oh16));
        }
    }
}

// ---------------------------------------------------------------------------
extern "C" void kernel_launch(void* const* d_in, const int* in_sizes, int n_in,
                              void* d_out, int out_size, void* d_ws, size_t ws_size,
                              hipStream_t stream) {
    const float* q  = (const float*)d_in[0];
    const float* k  = (const float*)d_in[1];
    const float* v  = (const float*)d_in[2];
    const int* mask = (const int*)d_in[3];
    const float* Wq = (const float*)d_in[4];  const float* bq = (const float*)d_in[5];
    const float* Wk = (const float*)d_in[6];  const float* bk = (const float*)d_in[7];
    const float* Wv = (const float*)d_in[8];  const float* bv = (const float*)d_in[9];
    const float* Wo = (const float*)d_in[10]; const float* bo = (const float*)d_in[11];

    float* out    = (float*)d_out;                 // [B,S,D]
    float* scores = out + (size_t)B_ * S_ * D_;    // [B,H,S,S]

    const size_t NH = (size_t)B_ * H_ * S_ * DK_;  // 4.19M elems (== M_*D_)
    unsigned short* W = (unsigned short*)d_ws;
    unsigned short* q_hi = W + 0 * NH;
    unsigned short* q_lo = W + 1 * NH;
    unsigned short* k_hi = W + 2 * NH;
    unsigned short* k_lo = W + 3 * NH;
    unsigned short* vT   = W + 4 * NH;             // [B,H,DK,S] transposed
    // slots 7..12: X splits (live split->gemm_qkv); concat hi/lo aliases 7/8
    unsigned short* qXh = W + 7 * NH;  unsigned short* qXl = W + 8 * NH;
    unsigned short* kXh = W + 9 * NH;  unsigned short* kXl = W + 10 * NH;
    unsigned short* vXh = W + 11 * NH; unsigned short* vXl = W + 12 * NH;
    unsigned short* cat_h = qXh;       unsigned short* cat_l = qXl;   // reuse after gemm_qkv
    unsigned short* Wcat_h = W + 13 * NH;                 // [1536*512]
    unsigned short* Wcat_l = Wcat_h + 786432;
    unsigned short* Wo_h   = Wcat_l + 786432;             // [512*512]
    unsigned short* Wo_l   = Wo_h + 262144;
    unsigned long long* mbits = (unsigned long long*)(Wo_l + 262144);  // 2MB
    // ws use ~115 MB total

    split_x3<<<dim3(2048, 3), 256, 0, stream>>>(q, k, v, qXh, qXl, kXh, kXl, vXh, vXl);
    split_w4<<<dim3(128, 4), 256, 0, stream>>>(Wq, Wk, Wv, Wo, Wcat_h, Wcat_l, Wo_h, Wo_l);
    mask_pack<<<dim3(65536), 256, 0, stream>>>(mask, mbits);

    // fused QKV projections: N=1536, grid 64x12 = 768 blocks
    gemm_hl<<<dim3(64, 12), 256, 0, stream>>>(
        qXh, qXl, kXh, kXl, vXh, vXl, Wcat_h, Wcat_l, bq, bk, bv,
        nullptr, q_hi, q_lo, k_hi, k_lo, vT, 1);

    attn_mfma_kernel<<<dim3(S_ / 64, H_, B_), 256, 0, stream>>>(
        q_hi, q_lo, k_hi, k_lo, vT, mbits, scores, cat_h, cat_l);

    // output projection: N=512, fp32 out
    gemm_hl<<<dim3(64, 4), 256, 0, stream>>>(
        cat_h, cat_l, nullptr, nullptr, nullptr, nullptr, Wo_h, Wo_l, bo, nullptr, nullptr,
        out, nullptr, nullptr, nullptr, nullptr, nullptr, 0);
}